// Round 3
// baseline (347.692 us; speedup 1.0000x reference)
//
#include <hip/hip_runtime.h>
#include <hip/hip_bf16.h>
#include <math.h>

#define BDIM 32
#define HD   1024
#define SD   128
#define VD   32000

typedef __attribute__((ext_vector_type(8))) short short8;
typedef __attribute__((ext_vector_type(4))) float floatx4;

__device__ __forceinline__ short f2bf(float f) {
    unsigned u = __builtin_bit_cast(unsigned, f);
    u += 0x7FFFu + ((u >> 16) & 1u);
    return (short)(u >> 16);
}
__device__ __forceinline__ float bf2f(short h) {
    unsigned u = ((unsigned)(unsigned short)h) << 16;
    return __builtin_bit_cast(float, u);
}
// pack two fp32 -> one dword of two bf16 (round-half-up)
__device__ __forceinline__ unsigned pack2(float a, float b) {
    unsigned ua = __builtin_bit_cast(unsigned, a) + 0x8000u;
    unsigned ub = __builtin_bit_cast(unsigned, b) + 0x8000u;
    return (ub & 0xffff0000u) | (ua >> 16);
}

// swizzled layout for MFMA operand frags of a [32,K] activation:
// element M[b][k] at ((t*2+mt)*64 + q*16 + i)*8 + j
// t=k/32, q=(k%32)/8, j=k%8, mt=b/16, i=b%16.
// lane l reading short8 at ((t*2+mt)*64+l) gets element j =
// M[k=t*32+(l>>4)*8+j][b=mt*16+(l&15)] -- valid as A-frag and B-frag.
__device__ __forceinline__ int swz_idx(int b, int k) {
    int t = k >> 5, q = (k & 31) >> 3, j = k & 7;
    int mt = b >> 4, i = b & 15;
    return ((((t * 2 + mt) * 64) + q * 16 + i) << 3) + j;
}

#define MFMA(a, b, c) __builtin_amdgcn_mfma_f32_16x16x32_bf16(a, b, c, 0, 0, 0)

// ---------------------------------------------------------------------------
// prep_swz: swizzle x0/h0 into hi/lo bf16 fragment layouts
// ---------------------------------------------------------------------------
__global__ __launch_bounds__(256) void prep_swz(
    const float* __restrict__ x0, const float* __restrict__ h0,
    short* __restrict__ x0h, short* __restrict__ x0l,
    short* __restrict__ h0h, short* __restrict__ h0l)
{
    int idx = blockIdx.x * 256 + threadIdx.x;
    if (idx < 32768) {
        int b = idx >> 10, k = idx & 1023;
        float xv = x0[idx]; short hh = f2bf(xv);
        int d = swz_idx(b, k);
        x0h[d] = hh; x0l[d] = f2bf(xv - bf2f(hh));
    } else {
        idx -= 32768;
        int b = idx >> 10, k = idx & 1023;
        float xv = h0[idx]; short hh = f2bf(xv);
        int d = swz_idx(b, k);
        h0h[d] = hh; h0l[d] = f2bf(xv - bf2f(hh));
    }
}

// ---------------------------------------------------------------------------
// gates GEMM: out[b][n] += sum_k act[b][k]*W[n][k], act swizzled hi/lo global
// ---------------------------------------------------------------------------
template<int KCHUNK>
__device__ __forceinline__ void gemm_gates_body(
    const short* __restrict__ bhi, const short* __restrict__ blo,
    const float* __restrict__ W, float* __restrict__ out, int N, int K, int k0)
{
    int tid = threadIdx.x;
    int w = tid >> 6, l = tid & 63;
    int i = l & 15, q = l >> 4;
    int n0 = blockIdx.x * 64 + w * 16;
    const float* wrow = W + (size_t)(n0 + i) * K + q * 8;
    const short8* bph = (const short8*)bhi + l;
    const short8* bpl = (const short8*)blo + l;

    floatx4 acc0 = {0.f, 0.f, 0.f, 0.f};
    floatx4 acc1 = {0.f, 0.f, 0.f, 0.f};

#pragma unroll 2
    for (int kk = k0; kk < k0 + KCHUNK; kk += 32) {
        float4 w0 = *(const float4*)(wrow + kk);
        float4 w1 = *(const float4*)(wrow + kk + 4);
        float wf[8] = {w0.x, w0.y, w0.z, w0.w, w1.x, w1.y, w1.z, w1.w};
        short8 ahi, alo;
#pragma unroll
        for (int j = 0; j < 8; ++j) {
            short hh = f2bf(wf[j]);
            ahi[j] = hh;
            alo[j] = f2bf(wf[j] - bf2f(hh));
        }
        int t2 = (kk >> 5) * 2;
        short8 b0 = bph[(size_t)t2 * 64];
        short8 b1 = bph[(size_t)(t2 + 1) * 64];
        short8 l0 = bpl[(size_t)t2 * 64];
        short8 l1 = bpl[(size_t)(t2 + 1) * 64];
        acc0 = MFMA(ahi, b0, acc0);
        acc1 = MFMA(ahi, b1, acc1);
        acc0 = MFMA(ahi, l0, acc0);
        acc1 = MFMA(ahi, l1, acc1);
        acc0 = MFMA(alo, b0, acc0);
        acc1 = MFMA(alo, b1, acc1);
    }

    __shared__ float lds[4][32][17];
#pragma unroll
    for (int r = 0; r < 4; ++r) {
        lds[w][i][q * 4 + r]      = acc0[r];   // lane holds D[m=q*4+r][n=i]
        lds[w][i + 16][q * 4 + r] = acc1[r];
    }
    __syncthreads();
    int b = l >> 1, hf = l & 1;
    size_t obase = (size_t)b * N + n0 + hf * 8;
#pragma unroll
    for (int t = 0; t < 8; ++t) atomicAdd(out + obase + t, lds[w][b][hf * 8 + t]);
}

__global__ __launch_bounds__(256) void gemm_gates(
    const short* __restrict__ x0h, const short* __restrict__ x0l,
    const short* __restrict__ h0h, const short* __restrict__ h0l,
    const float* __restrict__ W_ih, const float* __restrict__ W_hh,
    float* __restrict__ xg, float* __restrict__ hg)
{
    if (blockIdx.z == 0)
        gemm_gates_body<512>(x0h, x0l, W_ih, xg, 3072, 1024, blockIdx.y * 512);
    else
        gemm_gates_body<512>(h0h, h0l, W_hh, hg, 3072, 1024, blockIdx.y * 512);
}

// ---------------------------------------------------------------------------
// GRU gate fusion -> dec, written as hi/lo swizzled bf16 (biases added here)
// ---------------------------------------------------------------------------
__global__ __launch_bounds__(256) void gru_gate(
    const float* __restrict__ xg, const float* __restrict__ hg,
    const float* __restrict__ h0,
    const float* __restrict__ b_ih, const float* __restrict__ b_hh,
    short* __restrict__ dh, short* __restrict__ dl)
{
    int idx = blockIdx.x * 256 + threadIdx.x;   // 32*1024
    int b = idx >> 10, h = idx & 1023;
    const float* xp = xg + (size_t)b * 3072 + h;
    const float* hp = hg + (size_t)b * 3072 + h;
    float r = 1.f / (1.f + __expf(-(xp[0] + b_ih[h] + hp[0] + b_hh[h])));
    float z = 1.f / (1.f + __expf(-(xp[1024] + b_ih[1024 + h] +
                                    hp[1024] + b_hh[1024 + h])));
    // torch GRU: n = tanh(xg_n + b_ih_n + r*(hg_n + b_hh_n))
    float n = tanhf(xp[2048] + b_ih[2048 + h] + r * (hp[2048] + b_hh[2048 + h]));
    float dec = (1.f - z) * n + z * h0[idx];
    short hh = f2bf(dec);
    int d = swz_idx(b, h);
    dh[d] = hh; dl[d] = f2bf(dec - bf2f(hh));
}

// ---------------------------------------------------------------------------
// v[b][e] += sum_k dec[b][k] * Wa[k][1024+e] : LDS-staged, coalesced We reads
// ---------------------------------------------------------------------------
__global__ __launch_bounds__(256) void gemm_attn2(
    const short* __restrict__ dhi, const short* __restrict__ dlo,
    const float* __restrict__ Wa, float* __restrict__ v)
{
    int tid = threadIdx.x, w = tid >> 6, l = tid & 63;
    int i = l & 15, q = l >> 4;
    int e0 = blockIdx.x * 64;
    int k0 = blockIdx.y * 128;
    __shared__ float lds[32][65];

    const short8* ah = (const short8*)dhi;
    const short8* al = (const short8*)dlo;
    short8 Ah[4][2], Al[4][2];
#pragma unroll
    for (int t = 0; t < 4; ++t)
#pragma unroll
        for (int mt = 0; mt < 2; ++mt) {
            size_t idx = (size_t)((((k0 >> 5) + t) * 2 + mt) * 64) + l;
            Ah[t][mt] = ah[idx]; Al[t][mt] = al[idx];
        }

    floatx4 acc[2] = {{0.f,0.f,0.f,0.f},{0.f,0.f,0.f,0.f}};
    int sr = tid >> 3;          // 0..31 stage row
    int sc_ = (tid & 7) * 8;    // stage col
#pragma unroll
    for (int t = 0; t < 4; ++t) {
        const float* src = Wa + (size_t)(k0 + t * 32 + sr) * 2048 + 1024 + e0 + sc_;
        float4 s0 = *(const float4*)src;
        float4 s1 = *(const float4*)(src + 4);
        __syncthreads();
        *(float4*)&lds[sr][sc_]     = s0;
        *(float4*)&lds[sr][sc_ + 4] = s1;
        __syncthreads();
        short8 Bh, Bl;
#pragma unroll
        for (int j = 0; j < 8; ++j) {
            float f = lds[q * 8 + j][w * 16 + i];
            unsigned u = __builtin_bit_cast(unsigned, f);
            float hif = __builtin_bit_cast(float, u & 0xffff0000u);
            Bh[j] = (short)(u >> 16);
            float lo = f - hif;
            Bl[j] = (short)(__builtin_bit_cast(unsigned, lo) >> 16);
        }
        acc[0] = MFMA(Ah[t][0], Bh, acc[0]);
        acc[1] = MFMA(Ah[t][1], Bh, acc[1]);
        acc[0] = MFMA(Ah[t][0], Bl, acc[0]);
        acc[1] = MFMA(Ah[t][1], Bl, acc[1]);
        acc[0] = MFMA(Al[t][0], Bh, acc[0]);
        acc[1] = MFMA(Al[t][1], Bh, acc[1]);
    }
#pragma unroll
    for (int mt = 0; mt < 2; ++mt)
#pragma unroll
        for (int r = 0; r < 4; ++r)
            atomicAdd(v + (size_t)(mt * 16 + q * 4 + r) * 1024 + e0 + w * 16 + i,
                      acc[mt][r]);
}

// ---------------------------------------------------------------------------
// fused scores+softmax(shift-free)+context partials. grid (16 s-chunks, 32 b).
// den[b] += sum exp(score); num[b][e] += sum exp(score)*enc; es stored raw.
// ---------------------------------------------------------------------------
__global__ __launch_bounds__(256) void scores_ctx(
    const float* __restrict__ v, const float* __restrict__ enc,
    float* __restrict__ num, float* __restrict__ den, float* __restrict__ es)
{
    int b = blockIdx.y, tid = threadIdx.x;
    int s0 = blockIdx.x * 8;
    int w = tid >> 6, l = tid & 63;
    float4 vv = *((const float4*)(v + (size_t)b * 1024) + tid);
    float4 e8[8];
    float part[8];
#pragma unroll
    for (int s = 0; s < 8; ++s) {
        float4 e4 = *((const float4*)(enc + ((size_t)(s0 + s) * BDIM + b) * 1024) + tid);
        e8[s] = e4;
        part[s] = e4.x * vv.x + e4.y * vv.y + e4.z * vv.z + e4.w * vv.w;
    }
    __shared__ float red[4][8];
    __shared__ float esl[8];
#pragma unroll
    for (int s = 0; s < 8; ++s) {
        float p = part[s];
        for (int o = 32; o; o >>= 1) p += __shfl_down(p, o);
        if (l == 0) red[w][s] = p;
    }
    __syncthreads();
    if (tid < 8) {
        float sc = red[0][tid] + red[1][tid] + red[2][tid] + red[3][tid];
        float e = __expf(sc);
        esl[tid] = e;
        es[b * SD + s0 + tid] = e;
    }
    __syncthreads();
    if (tid == 0) {
        float ds = 0.f;
#pragma unroll
        for (int s = 0; s < 8; ++s) ds += esl[s];
        atomicAdd(den + b, ds);
    }
    float n0 = 0.f, n1 = 0.f, n2 = 0.f, n3 = 0.f;
#pragma unroll
    for (int s = 0; s < 8; ++s) {
        float e = esl[s];
        n0 += e * e8[s].x; n1 += e * e8[s].y;
        n2 += e * e8[s].z; n3 += e * e8[s].w;
    }
    float* np = num + (size_t)b * 1024 + tid * 4;
    atomicAdd(np, n0); atomicAdd(np + 1, n1);
    atomicAdd(np + 2, n2); atomicAdd(np + 3, n3);
}

// ---------------------------------------------------------------------------
// comb GEMM: cat built in-block (x0 fp32 / num-den normalize) -> LDS frags.
// block (n-tile 0..15, k-chunk 0..7 of 256). Block x==0 also writes aw_out.
// ---------------------------------------------------------------------------
__global__ __launch_bounds__(256) void gemm_comb2(
    const float* __restrict__ x0, const float* __restrict__ num,
    const float* __restrict__ den, const float* __restrict__ es,
    const float* __restrict__ W_comb, float* __restrict__ comb,
    float* __restrict__ aw_out)
{
    int tid = threadIdx.x;
    int w = tid >> 6, l = tid & 63;
    int i = l & 15, q = l >> 4;
    int n0 = blockIdx.x * 64 + w * 16;
    int k0 = blockIdx.y * 256;
    __shared__ short cfrag[8192];   // 32 b x 256 k, swizzled (local k)

    if (blockIdx.x == 0) {          // attn_weights output, 512 elems per y
        int base = blockIdx.y * 512 + tid * 2;
#pragma unroll
        for (int j = 0; j < 2; ++j) {
            int idx = base + j;
            aw_out[idx] = es[idx] / den[idx >> 7];
        }
    }
    for (int ii = tid; ii < 8192; ii += 256) {
        int b = ii >> 8, kl = ii & 255;
        int k = k0 + kl;
        float xv = (k < 1024) ? x0[(b << 10) + k]
                              : num[(b << 10) + (k & 1023)] / den[b];
        cfrag[swz_idx(b, kl)] = f2bf(xv);
    }
    __syncthreads();

    const float* wrow = W_comb + (size_t)(n0 + i) * 2048 + k0 + q * 8;
    const short8* bp = (const short8*)cfrag + l;
    floatx4 acc0 = {0.f, 0.f, 0.f, 0.f};
    floatx4 acc1 = {0.f, 0.f, 0.f, 0.f};
#pragma unroll 2
    for (int kl = 0; kl < 256; kl += 32) {
        float4 w0 = *(const float4*)(wrow + kl);
        float4 w1 = *(const float4*)(wrow + kl + 4);
        union { unsigned u[4]; short8 s; } pk;
        pk.u[0] = pack2(w0.x, w0.y);
        pk.u[1] = pack2(w0.z, w0.w);
        pk.u[2] = pack2(w1.x, w1.y);
        pk.u[3] = pack2(w1.z, w1.w);
        int t2 = (kl >> 5) * 2;
        short8 b0 = bp[t2 * 64];
        short8 b1 = bp[(t2 + 1) * 64];
        acc0 = MFMA(pk.s, b0, acc0);
        acc1 = MFMA(pk.s, b1, acc1);
    }
    __shared__ float lds[4][32][17];
#pragma unroll
    for (int r = 0; r < 4; ++r) {
        lds[w][i][q * 4 + r]      = acc0[r];
        lds[w][i + 16][q * 4 + r] = acc1[r];
    }
    __syncthreads();
    int b = l >> 1, hf = l & 1;
    size_t obase = (size_t)b * 1024 + n0 + hf * 8;
#pragma unroll
    for (int t = 0; t < 8; ++t) atomicAdd(comb + obase + t, lds[w][b][hf * 8 + t]);
}

// ---------------------------------------------------------------------------
// vocab GEMM: converts comb(+b_comb) -> swizzled bf16 LDS in-block, then
// out[b][v] = comb.W_out[v] + b_out[v]; accumulates per-b sum(exp) into sexp.
// ---------------------------------------------------------------------------
__global__ __launch_bounds__(256) void gemm_out2(
    const float* __restrict__ comb, const float* __restrict__ b_comb,
    const float* __restrict__ W, const float* __restrict__ bias,
    float* __restrict__ out, float* __restrict__ sexp)
{
    int tid = threadIdx.x, w = tid >> 6, l = tid & 63;
    int i = l & 15, q = l >> 4;
    int n0 = blockIdx.x * 64 + w * 16;
    __shared__ short cfrag[32768];      // 32 b x 1024 k swizzled
    __shared__ float lds[4][32][17];
    __shared__ float bsum[32];
    if (tid < 32) bsum[tid] = 0.f;
    for (int ii = tid; ii < 32768; ii += 256) {
        int b = ii >> 10, k = ii & 1023;
        cfrag[swz_idx(b, k)] = f2bf(comb[ii] + b_comb[k]);
    }
    __syncthreads();

    const float* wrow = W + (size_t)(n0 + i) * 1024 + q * 8;
    const short8* bp = (const short8*)cfrag + l;
    floatx4 acc0 = {0.f, 0.f, 0.f, 0.f};
    floatx4 acc1 = {0.f, 0.f, 0.f, 0.f};
#pragma unroll 4
    for (int kk = 0; kk < 1024; kk += 32) {
        float4 w0 = *(const float4*)(wrow + kk);
        float4 w1 = *(const float4*)(wrow + kk + 4);
        union { unsigned u[4]; short8 s; } pk;
        pk.u[0] = pack2(w0.x, w0.y);
        pk.u[1] = pack2(w0.z, w0.w);
        pk.u[2] = pack2(w1.x, w1.y);
        pk.u[3] = pack2(w1.z, w1.w);
        int t2 = (kk >> 5) * 2;
        short8 b0 = bp[t2 * 64];
        short8 b1 = bp[(t2 + 1) * 64];
        acc0 = MFMA(pk.s, b0, acc0);
        acc1 = MFMA(pk.s, b1, acc1);
    }
#pragma unroll
    for (int r = 0; r < 4; ++r) {
        lds[w][i][q * 4 + r]      = acc0[r];
        lds[w][i + 16][q * 4 + r] = acc1[r];
    }
    __syncthreads();
    int b = l >> 1, hf = l & 1;
    float vo[8];
#pragma unroll
    for (int t = 0; t < 8; ++t) vo[t] = lds[w][b][hf * 8 + t];
    const float4* bp4 = (const float4*)(bias + n0 + hf * 8);
    float4 bb0 = bp4[0], bb1 = bp4[1];
    vo[0] += bb0.x; vo[1] += bb0.y; vo[2] += bb0.z; vo[3] += bb0.w;
    vo[4] += bb1.x; vo[5] += bb1.y; vo[6] += bb1.z; vo[7] += bb1.w;
    float esum = 0.f;
#pragma unroll
    for (int t = 0; t < 8; ++t) esum += __expf(vo[t]);
    atomicAdd(&bsum[b], esum);
    float4 o0 = {vo[0], vo[1], vo[2], vo[3]};
    float4 o1 = {vo[4], vo[5], vo[6], vo[7]};
    float4* op = (float4*)(out + (size_t)b * VD + n0 + hf * 8);
    op[0] = o0; op[1] = o1;
    __syncthreads();
    if (tid < 32) atomicAdd(sexp + tid, bsum[tid]);
}

__global__ __launch_bounds__(256) void final_k(
    float* __restrict__ out, const float* __restrict__ sexp)
{
    int b = blockIdx.y;
    int vv = blockIdx.x * 256 + threadIdx.x;
    size_t o = (size_t)b * VD + vv;
    out[o] -= logf(sexp[b]);
}

// ---------------------------------------------------------------------------
extern "C" void kernel_launch(void* const* d_in, const int* in_sizes, int n_in,
                              void* d_out, int out_size, void* d_ws, size_t ws_size,
                              hipStream_t stream) {
    const float* x      = (const float*)d_in[0];
    const float* enc    = (const float*)d_in[1];
    const float* hid    = (const float*)d_in[2];
    const float* W_ih   = (const float*)d_in[3];
    const float* W_hh   = (const float*)d_in[4];
    const float* b_ih   = (const float*)d_in[5];
    const float* b_hh   = (const float*)d_in[6];
    const float* W_attn = (const float*)d_in[7];
    const float* W_comb = (const float*)d_in[9];
    const float* b_comb = (const float*)d_in[10];
    const float* W_out  = (const float*)d_in[11];
    const float* b_out  = (const float*)d_in[12];
    float* out = (float*)d_out;

    // zero-init region (single memset): xg hg v num den sexp comb
    float* wsf  = (float*)d_ws;
    float* xg   = wsf;                  // 98304
    float* hg   = xg + 98304;           // 98304
    float* v    = hg + 98304;           // 32768
    float* num  = v + 32768;            // 32768
    float* den  = num + 32768;          // 32
    float* sexp = den + 32;             // 32
    float* comb = sexp + 32;            // 32768
    size_t zcount = 98304u * 2 + 32768u * 3 + 64;   // floats
    // non-zeroed scratch
    float* es   = comb + 32768;         // 4096
    short* x0h  = (short*)(es + 4096);
    short* x0l  = x0h + 32768;
    short* h0h  = x0l + 32768;
    short* h0l  = h0h + 32768;
    short* dh   = h0l + 32768;
    short* dl   = dh + 32768;

    hipMemsetAsync(wsf, 0, zcount * sizeof(float), stream);
    prep_swz<<<256, 256, 0, stream>>>(x, hid, x0h, x0l, h0h, h0l);
    gemm_gates<<<dim3(48, 2, 2), 256, 0, stream>>>(
        x0h, x0l, h0h, h0l, W_ih, W_hh, xg, hg);
    gru_gate<<<128, 256, 0, stream>>>(xg, hg, hid, b_ih, b_hh, dh, dl);
    gemm_attn2<<<dim3(16, 8), 256, 0, stream>>>(dh, dl, W_attn, v);
    scores_ctx<<<dim3(16, 32), 256, 0, stream>>>(v, enc, num, den, es);
    gemm_comb2<<<dim3(16, 8), 256, 0, stream>>>(
        x, num, den, es, W_comb, comb, out + 1024000);
    gemm_out2<<<500, 256, 0, stream>>>(comb, b_comb, W_out, b_out, out, sexp);
    final_k<<<dim3(125, 32), 256, 0, stream>>>(out, sexp);
}